// Round 3
// baseline (314.963 us; speedup 1.0000x reference)
//
#include <hip/hip_runtime.h>

// ---------------------------------------------------------------------------
// Fully-fused MFMA implementation with split-bf16 (hi+lo) precision on the
// location branch (s -> hl -> centroids), plain bf16 on the value branch.
//   GEMM1:  [16 x K32] s @ [K32 x 208]  (W1|L1 cols, bias folded as k=10 row)
//           tiles 0-5 (W1): 1-term; tiles 6-12 (L1): 3-term split
//   GEMM2a: hv [16 x K128] @ [K128 x 32] -> values (bias as k=100), 1-term
//   GEMM2b: hl [16 x K128] @ [K128 x 64] -> centroids, 3-term split
// Each wave owns 64 samples (4 M-tiles of 16); h round-trips through
// XOR-swizzled per-wave LDS regions; epilogue in-register via shfl.
// ---------------------------------------------------------------------------

typedef __attribute__((ext_vector_type(8))) short bf16x8;
typedef __attribute__((ext_vector_type(4))) float f32x4;

#define B1L_BASE 6656
#define B2H_BASE 10240
#define B3H_BASE 14336
#define B3L_BASE 22528
#define H_BASE   30720
#define LDS_SHORTS (30720 + 4 * 6144)     // 55296 shorts = 110592 bytes
#define LDS_BYTES (LDS_SHORTS * 2)

__device__ __forceinline__ short f2bf(float x) {
    union { float f; unsigned u; } v; v.f = x;
    unsigned r = v.u + 0x7FFFu + ((v.u >> 16) & 1u);   // RNE
    return (short)(r >> 16);
}
__device__ __forceinline__ float bf2f(short h) {
    union { unsigned u; float f; } v; v.u = ((unsigned)(unsigned short)h) << 16;
    return v.f;
}
__device__ __forceinline__ float tanh_fast(float x) {
    float e = __expf(2.f * x);
    return 1.f - 2.f / (e + 1.f);
}
// swizzled short-index inside a [16 rows][128 cols] bf16 region
__device__ __forceinline__ int swz(int row, int col) {
    int b = row * 256 + col * 2;
    b ^= (row & 7) << 4;
    return b >> 1;
}

__global__ __launch_bounds__(256, 1) void fused_kernel(
    const float* __restrict__ s, const float* __restrict__ a,
    const float* __restrict__ W1, const float* __restrict__ b1,
    const float* __restrict__ W2, const float* __restrict__ b2,
    const float* __restrict__ L1, const float* __restrict__ bl1,
    const float* __restrict__ WL2, const float* __restrict__ bL2,
    float* __restrict__ out)
{
    extern __shared__ short lds[];
    const int tid  = threadIdx.x;
    const int lane = tid & 63;
    const int wave = tid >> 6;
    const int j16  = lane & 15;
    const int g    = lane >> 4;
    const int wgbase = blockIdx.x * 256;

    // ---- stage GEMM1 B (hi for all 13 tiles, lo for tiles 6-12) ----
    for (int idx = tid; idx < 6656; idx += 256) {
        int t = idx >> 9, rem = idx & 511;
        int ln = rem >> 3, j = rem & 7;
        int k = ((ln >> 4) << 3) + j;
        int c = t * 16 + (ln & 15);
        float val = 0.f;
        if (c < 200) {
            int cc = (c < 100) ? c : c - 100;
            const float* w  = (c < 100) ? W1 : L1;
            const float* bb = (c < 100) ? b1 : bl1;
            if (k < 10) val = w[k * 100 + cc];
            else if (k == 10) val = bb[cc];
        }
        short hi = f2bf(val);
        lds[idx] = hi;
        if (t >= 6) lds[B1L_BASE + (t - 6) * 512 + rem] = f2bf(val - bf2f(hi));
    }
    // ---- stage GEMM2a B (hi only): [2 tiles][4 kt][512] ----
    for (int idx = tid; idx < 4096; idx += 256) {
        int t = idx >> 11, r2 = idx & 2047;
        int kt = r2 >> 9, rem = r2 & 511;
        int ln = rem >> 3, j = rem & 7;
        int k = kt * 32 + ((ln >> 4) << 3) + j;
        int c = t * 16 + (ln & 15);
        float val = 0.f;
        if (c < 30) {
            if (k < 100) val = W2[k * 30 + c];
            else if (k == 100) val = b2[c];
        }
        lds[B2H_BASE + idx] = f2bf(val);
    }
    // ---- stage GEMM2b B (hi + lo): [4 tiles][4 kt][512] ----
    for (int idx = tid; idx < 8192; idx += 256) {
        int t = idx >> 11, r3 = idx & 2047;
        int kt = r3 >> 9, rem = r3 & 511;
        int ln = rem >> 3, j = rem & 7;
        int k = kt * 32 + ((ln >> 4) << 3) + j;
        int c = t * 16 + (ln & 15);
        int n = c >> 1, d = c & 1;
        float val = 0.f;
        if (n < 30) {
            if (k < 100) val = WL2[(n * 100 + k) * 2 + d];
            else if (k == 100) val = bL2[n * 2 + d];
        }
        short hi = f2bf(val);
        lds[B3H_BASE + idx] = hi;
        lds[B3L_BASE + idx] = f2bf(val - bf2f(hi));
    }

    // ---- per-wave h regions: hv @+0, hlhi @+2048, hllo @+4096 (shorts) ----
    short* hw = lds + H_BASE + wave * 6144;
    // init constant cols 100..127 of each region (bias 1.0 at col 100 of hv/hlhi)
    for (int i = lane; i < 1344; i += 64) {
        int reg = i / 448, rem = i % 448;
        int row = rem / 28, col = 100 + rem % 28;
        float v = (col == 100 && reg < 2) ? 1.f : 0.f;
        hw[reg * 2048 + swz(row, col)] = f2bf(v);
    }
    __syncthreads();

    const f32x4 fzero = {0.f, 0.f, 0.f, 0.f};

    for (int mt = 0; mt < 4; ++mt) {
        const int m0 = wave * 64 + mt * 16;

        // ---- A fragments of s (hi + lo); k=10 is bias row (exact 1.0) ----
        bf16x8 af_hi, af_lo;
        #pragma unroll
        for (int i = 0; i < 8; ++i) { af_hi[i] = 0; af_lo[i] = 0; }
        {
            const float2* p = (const float2*)(s + (size_t)(wgbase + m0 + j16) * 10);
            if (g == 0) {
                float2 q[4] = {p[0], p[1], p[2], p[3]};
                #pragma unroll
                for (int i = 0; i < 4; ++i) {
                    short hx = f2bf(q[i].x), hy = f2bf(q[i].y);
                    af_hi[2 * i]     = hx; af_lo[2 * i]     = f2bf(q[i].x - bf2f(hx));
                    af_hi[2 * i + 1] = hy; af_lo[2 * i + 1] = f2bf(q[i].y - bf2f(hy));
                }
            } else if (g == 1) {
                float2 p4 = p[4];
                short hx = f2bf(p4.x), hy = f2bf(p4.y);
                af_hi[0] = hx; af_lo[0] = f2bf(p4.x - bf2f(hx));
                af_hi[1] = hy; af_lo[1] = f2bf(p4.y - bf2f(hy));
                af_hi[2] = (short)0x3F80;   // k = 10 -> 1.0 (bias row), lo = 0
            }
        }

        // ---- GEMM1 ----
        f32x4 dv[13];
        #pragma unroll
        for (int t = 0; t < 6; ++t) {
            bf16x8 bh = *(const bf16x8*)(lds + t * 512 + lane * 8);
            dv[t] = __builtin_amdgcn_mfma_f32_16x16x32_bf16(af_hi, bh, fzero, 0, 0, 0);
        }
        #pragma unroll
        for (int t = 6; t < 13; ++t) {
            bf16x8 bh = *(const bf16x8*)(lds + t * 512 + lane * 8);
            bf16x8 bl = *(const bf16x8*)(lds + B1L_BASE + (t - 6) * 512 + lane * 8);
            f32x4 d = __builtin_amdgcn_mfma_f32_16x16x32_bf16(af_hi, bh, fzero, 0, 0, 0);
            d = __builtin_amdgcn_mfma_f32_16x16x32_bf16(af_lo, bh, d, 0, 0, 0);
            d = __builtin_amdgcn_mfma_f32_16x16x32_bf16(af_hi, bl, d, 0, 0, 0);
            dv[t] = d;
        }

        // ---- relu -> h regions (hv: bf16; hl: hi+lo) ----
        #pragma unroll
        for (int t = 0; t < 13; ++t) {
            int c = t * 16 + j16;
            if (c < 100) {
                #pragma unroll
                for (int r = 0; r < 4; ++r)
                    hw[swz(g * 4 + r, c)] = f2bf(fmaxf(dv[t][r], 0.f));
            } else if (c < 200) {
                int cc = c - 100;
                #pragma unroll
                for (int r = 0; r < 4; ++r) {
                    float v = fmaxf(dv[t][r], 0.f);
                    short hi = f2bf(v);
                    hw[2048 + swz(g * 4 + r, cc)] = hi;
                    hw[4096 + swz(g * 4 + r, cc)] = f2bf(v - bf2f(hi));
                }
            }
        }

        // ---- GEMM2: values (1-term) + centroids (3-term), K=128 ----
        f32x4 dvals[2] = {fzero, fzero};
        f32x4 dcent[4] = {fzero, fzero, fzero, fzero};
        #pragma unroll
        for (int kt = 0; kt < 4; ++kt) {
            bf16x8 ahv = *(const bf16x8*)(hw + swz(j16, kt * 32 + g * 8));
            bf16x8 ahi = *(const bf16x8*)(hw + 2048 + swz(j16, kt * 32 + g * 8));
            bf16x8 alo = *(const bf16x8*)(hw + 4096 + swz(j16, kt * 32 + g * 8));
            #pragma unroll
            for (int t = 0; t < 2; ++t) {
                bf16x8 bw = *(const bf16x8*)(lds + B2H_BASE + (t * 4 + kt) * 512 + lane * 8);
                dvals[t] = __builtin_amdgcn_mfma_f32_16x16x32_bf16(ahv, bw, dvals[t], 0, 0, 0);
            }
            #pragma unroll
            for (int t = 0; t < 4; ++t) {
                bf16x8 bh = *(const bf16x8*)(lds + B3H_BASE + (t * 4 + kt) * 512 + lane * 8);
                bf16x8 bl = *(const bf16x8*)(lds + B3L_BASE + (t * 4 + kt) * 512 + lane * 8);
                dcent[t] = __builtin_amdgcn_mfma_f32_16x16x32_bf16(ahi, bh, dcent[t], 0, 0, 0);
                dcent[t] = __builtin_amdgcn_mfma_f32_16x16x32_bf16(alo, bh, dcent[t], 0, 0, 0);
                dcent[t] = __builtin_amdgcn_mfma_f32_16x16x32_bf16(ahi, bl, dcent[t], 0, 0, 0);
            }
        }

        // ---- epilogue: tanh, dist, softmax, weighted sum ----
        #pragma unroll
        for (int r = 0; r < 4; ++r) {
            int mloc = m0 + g * 4 + r;
            float2 av = ((const float2*)a)[wgbase + mloc];
            float t5[4];
            #pragma unroll
            for (int t = 0; t < 4; ++t) t5[t] = 5.f * tanh_fast(dcent[t][r]);

            float num = 0.f, den = 0.f;
            #pragma unroll
            for (int t = 0; t < 4; ++t) {
                float pr = __shfl_xor(t5[t], 1);
                float cx = (j16 & 1) ? pr : t5[t];
                float cy = (j16 & 1) ? t5[t] : pr;
                float ex = cx - av.x, ey = cy - av.y;
                float dist = sqrtf(fmaf(ex, ex, ey * ey));
                int n = 8 * t + (j16 >> 1);
                float wt = (n < 30) ? __expf(-3.f * dist) : 0.f;
                int src = (lane & 48) + ((t & 1) << 3) + (j16 >> 1);
                float vf = __shfl((t >= 2) ? dvals[1][r] : dvals[0][r], src, 64);
                num = fmaf(wt, vf, num);
                den += wt;
            }
            #pragma unroll
            for (int m = 2; m <= 8; m <<= 1) {
                num += __shfl_xor(num, m);
                den += __shfl_xor(den, m);
            }
            if (j16 == 0) out[wgbase + mloc] = num / den;
        }
    }
}

extern "C" void kernel_launch(void* const* d_in, const int* in_sizes, int n_in,
                              void* d_out, int out_size, void* d_ws, size_t ws_size,
                              hipStream_t stream) {
    const float* s   = (const float*)d_in[0];
    const float* a   = (const float*)d_in[1];
    const float* W1  = (const float*)d_in[2];
    const float* b1  = (const float*)d_in[3];
    const float* W2  = (const float*)d_in[4];
    const float* b2  = (const float*)d_in[5];
    const float* L1  = (const float*)d_in[6];
    const float* bl1 = (const float*)d_in[7];
    const float* WL2 = (const float*)d_in[8];
    const float* bL2 = (const float*)d_in[9];
    float* out = (float*)d_out;

    int Btot = out_size;                 // 524288
    int grid = Btot / 256;               // 2048 workgroups, 64 samples/wave
    fused_kernel<<<grid, 256, LDS_BYTES, stream>>>(s, a, W1, b1, W2, b2, L1, bl1, WL2, bL2, out);
}

// Round 4
// 160.840 us; speedup vs baseline: 1.9582x; 1.9582x over previous
//
#include <hip/hip_runtime.h>

// ---------------------------------------------------------------------------
// Operand-swapped fully-fused MFMA kernel, zero h-LDS.
//   GEMM1': D[c][m] = (W|b)^T s^T   -> h in "transposed C layout"
//           value branch 1-term; location branch 3-term (hi/lo split)
//   exchange: pack h to bf16 pairs, 8 shfl + selects per kt per stream
//   GEMM2': D[n][m] = W2^T h^T (values), WL2^T h^T (centroids, 3-term)
//           row mapping chosen so each lane ends with complete
//           (x, y, value) triples for 8 centroids of its own sample m.
// Weight fragments precomputed once into d_ws by prep_kernel; main kernel
// copies ws -> LDS (50.5 KB -> 3 WG/CU) and has NO barriers in the mt loop.
// ---------------------------------------------------------------------------

typedef __attribute__((ext_vector_type(8))) short bf16x8;
typedef __attribute__((ext_vector_type(4))) float f32x4;

// short-index offsets inside ws / LDS
#define OFF_V1  0        // 7 half-tiles x 256 (value GEMM1' A, hi)
#define OFF_L1H 1792     // 7 half-tiles x 256 (loc GEMM1' A, hi)
#define OFF_L1L 3584     // 7 half-tiles x 256 (loc GEMM1' A, lo)
#define OFF_W2  5376     // 2 n-tiles x 4 kt x 512 (values GEMM2' A, hi)
#define OFF_W3H 9472     // 4 c-tiles x 4 kt x 512 (centroid GEMM2' A, hi)
#define OFF_W3L 17664    // same, lo
#define TOT_SHORTS 25856 // 51712 bytes

__device__ __forceinline__ short f2bf(float x) {
    union { float f; unsigned u; } v; v.f = x;
    unsigned r = v.u + 0x7FFFu + ((v.u >> 16) & 1u);   // RNE
    return (short)(r >> 16);
}
__device__ __forceinline__ float bf2f(short h) {
    union { unsigned u; float f; } v; v.u = ((unsigned)(unsigned short)h) << 16;
    return v.f;
}
__device__ __forceinline__ unsigned pack2(short lo, short hi) {
    return (unsigned)(unsigned short)lo | (((unsigned)(unsigned short)hi) << 16);
}
__device__ __forceinline__ float tanh_fast(float x) {
    float e = __expf(2.f * x);
    return 1.f - 2.f / (e + 1.f);
}

// ---------------- prologue: build fragment-layout weights in ws ------------
__global__ __launch_bounds__(256) void prep_kernel(
    const float* __restrict__ W1, const float* __restrict__ b1,
    const float* __restrict__ W2, const float* __restrict__ b2,
    const float* __restrict__ L1, const float* __restrict__ bl1,
    const float* __restrict__ WL2, const float* __restrict__ bL2,
    short* __restrict__ ws)
{
    int idx = blockIdx.x * 256 + threadIdx.x;
    if (idx >= TOT_SHORTS) return;
    float val = 0.f;
    bool want_lo = false;

    if (idx < OFF_W2) {
        // GEMM1' A half-tiles: [region r][tile t][lane 0..31][j 0..7]
        int r = idx / 1792;              // 0 = W1(hi), 1 = L1(hi), 2 = L1(lo)
        int rem = idx - r * 1792;
        int t = rem >> 8, e = rem & 255;
        int ln = e >> 3, j = e & 7;      // ln 0..31
        int c = t * 16 + (ln & 15);      // hidden unit (row of A)
        int k = (ln >> 4) * 8 + j;       // 0..15 (real k: 0..10)
        const float* W  = (r == 0) ? W1 : L1;
        const float* bb = (r == 0) ? b1 : bl1;
        if (c < 100)       val = (k < 10) ? W[k * 100 + c] : ((k == 10) ? bb[c] : 0.f);
        else if (c == 100) val = (k == 10) ? 1.f : 0.f;    // generates h[100]=1 bias row
        want_lo = (r == 2);
    } else if (idx < OFF_W3H) {
        // GEMM2a' A: [T 0..1][kt 0..3][lane 0..63][j]
        int i2 = idx - OFF_W2;
        int T = i2 >> 11, kt = (i2 >> 9) & 3, e = i2 & 511;
        int ln = e >> 3, j = e & 7;
        int rho = ln & 15;
        int k = kt * 32 + (ln >> 4) * 8 + j;
        int n = 16 * T + 2 * (rho >> 2) + ((rho & 3) >> 1) * 8 + (rho & 1);
        if (n < 30) val = (k < 100) ? W2[k * 30 + n] : ((k == 100) ? b2[n] : 0.f);
    } else {
        // GEMM2b' A: [half h][t 0..3][kt][lane][j]
        int i3 = idx - OFF_W3H;
        want_lo = (i3 >= 8192); i3 &= 8191;
        int t = i3 >> 11, kt = (i3 >> 9) & 3, e = i3 & 511;
        int ln = e >> 3, j = e & 7;
        int rho = ln & 15;
        int k = kt * 32 + (ln >> 4) * 8 + j;
        int n = 8 * t + 2 * (rho >> 2) + ((rho & 3) >> 1);
        int d = rho & 1;
        if (n < 30) val = (k < 100) ? WL2[(n * 100 + k) * 2 + d]
                                    : ((k == 100) ? bL2[n * 2 + d] : 0.f);
    }
    short hi = f2bf(val);
    ws[idx] = want_lo ? f2bf(val - bf2f(hi)) : hi;
}

// ---------------- main fused kernel ----------------------------------------
__global__ __launch_bounds__(256, 3) void fused_kernel(
    const float* __restrict__ s, const float* __restrict__ a,
    const short* __restrict__ ws, float* __restrict__ out)
{
    __shared__ short lds[TOT_SHORTS];
    const int tid  = threadIdx.x;
    const int lane = tid & 63;
    const int wave = tid >> 6;
    const int m    = lane & 15;
    const int G    = lane >> 4;
    const int wgbase = blockIdx.x * 256;

    // stage ws -> LDS (identity copy, 16B chunks)
    {
        const int4* g4 = (const int4*)ws;
        int4* l4 = (int4*)lds;
        for (int i = tid; i < TOT_SHORTS / 8; i += 256) l4[i] = g4[i];
    }
    __syncthreads();

    const int srcA = m | ((2 * (G & 1)) << 4);
    const int srcB = srcA | 16;
    const bool hiTile = (G >> 1) != 0;     // this lane's k-range lives in tile t0+1

    const bf16x8 bz = {0, 0, 0, 0, 0, 0, 0, 0};
    const f32x4 fz = {0.f, 0.f, 0.f, 0.f};

    for (int mt = 0; mt < 4; ++mt) {
        const int m0 = wave * 64 + mt * 16;

        // ---- B-frag of s^T (hi + lo); lanes>=32 zero; k=10 is bias-1 row ----
        bf16x8 sb_hi = bz, sb_lo = bz;
        {
            const float2* p = (const float2*)(s + (size_t)(wgbase + m0 + m) * 10);
            if (G == 0) {
                float2 q0 = p[0], q1 = p[1], q2 = p[2], q3 = p[3];
                float qs[8] = {q0.x, q0.y, q1.x, q1.y, q2.x, q2.y, q3.x, q3.y};
                #pragma unroll
                for (int i = 0; i < 8; ++i) {
                    short h = f2bf(qs[i]);
                    sb_hi[i] = h; sb_lo[i] = f2bf(qs[i] - bf2f(h));
                }
            } else if (G == 1) {
                float2 q4 = p[4];
                short hx = f2bf(q4.x), hy = f2bf(q4.y);
                sb_hi[0] = hx; sb_lo[0] = f2bf(q4.x - bf2f(hx));
                sb_hi[1] = hy; sb_lo[1] = f2bf(q4.y - bf2f(hy));
                sb_hi[2] = (short)0x3F80;  // k = 10 -> 1.0
            }
        }

        // ---- GEMM1' + relu + pack to bf16 pairs -----------------------------
        unsigned pv0[7], pv1[7], ph0[7], ph1[7], pl0[7], pl1[7];
        #pragma unroll
        for (int t = 0; t < 7; ++t) {
            bf16x8 aV = bz, aH = bz, aL = bz;
            if (lane < 32) {
                aV = *(const bf16x8*)(lds + OFF_V1  + t * 256 + lane * 8);
                aH = *(const bf16x8*)(lds + OFF_L1H + t * 256 + lane * 8);
                aL = *(const bf16x8*)(lds + OFF_L1L + t * 256 + lane * 8);
            }
            f32x4 dv = __builtin_amdgcn_mfma_f32_16x16x32_bf16(aV, sb_hi, fz, 0, 0, 0);
            f32x4 dh = __builtin_amdgcn_mfma_f32_16x16x32_bf16(aH, sb_hi, fz, 0, 0, 0);
            dh = __builtin_amdgcn_mfma_f32_16x16x32_bf16(aH, sb_lo, dh, 0, 0, 0);
            dh = __builtin_amdgcn_mfma_f32_16x16x32_bf16(aL, sb_hi, dh, 0, 0, 0);

            float v0 = fmaxf(dv[0], 0.f), v1 = fmaxf(dv[1], 0.f);
            float v2 = fmaxf(dv[2], 0.f), v3 = fmaxf(dv[3], 0.f);
            pv0[t] = pack2(f2bf(v0), f2bf(v1));
            pv1[t] = pack2(f2bf(v2), f2bf(v3));

            float h0 = fmaxf(dh[0], 0.f), h1 = fmaxf(dh[1], 0.f);
            float h2 = fmaxf(dh[2], 0.f), h3 = fmaxf(dh[3], 0.f);
            short h0h = f2bf(h0), h1h = f2bf(h1), h2h = f2bf(h2), h3h = f2bf(h3);
            ph0[t] = pack2(h0h, h1h);
            ph1[t] = pack2(h2h, h3h);
            pl0[t] = pack2(f2bf(h0 - bf2f(h0h)), f2bf(h1 - bf2f(h1h)));
            pl1[t] = pack2(f2bf(h2 - bf2f(h2h)), f2bf(h3 - bf2f(h3h)));
        }

        // ---- exchange helper: build GEMM2' B-frag for one kt ----------------
        auto xch4 = [&](unsigned a0, unsigned a1, unsigned b0, unsigned b1,
                        bool hasT1) -> bf16x8 {
            unsigned e0 = (unsigned)__shfl((int)a0, srcA);
            unsigned e1 = (unsigned)__shfl((int)a1, srcA);
            unsigned e2 = (unsigned)__shfl((int)a0, srcB);
            unsigned e3 = (unsigned)__shfl((int)a1, srcB);
            unsigned f0 = 0, f1 = 0, f2 = 0, f3 = 0;
            if (hasT1) {
                f0 = (unsigned)__shfl((int)b0, srcA);
                f1 = (unsigned)__shfl((int)b1, srcA);
                f2 = (unsigned)__shfl((int)b0, srcB);
                f3 = (unsigned)__shfl((int)b1, srcB);
            }
            union { unsigned u[4]; bf16x8 v; } U;
            U.u[0] = hiTile ? f0 : e0;
            U.u[1] = hiTile ? f1 : e1;
            U.u[2] = hiTile ? f2 : e2;
            U.u[3] = hiTile ? f3 : e3;
            return U.v;
        };

        // ---- GEMM2': K=128 in 4 kt steps ------------------------------------
        f32x4 DV[2] = {fz, fz};
        f32x4 DC[4] = {fz, fz, fz, fz};
        #pragma unroll
        for (int kt = 0; kt < 4; ++kt) {
            const bool h1 = (kt < 3);
            const int t0 = 2 * kt;
            const int t1 = h1 ? (2 * kt + 1) : 0;   // dummy 0 when absent

            bf16x8 bv = xch4(pv0[t0], pv1[t0], pv0[t1], pv1[t1], h1);
            bf16x8 bh = xch4(ph0[t0], ph1[t0], ph0[t1], ph1[t1], h1);
            bf16x8 bl = xch4(pl0[t0], pl1[t0], pl0[t1], pl1[t1], h1);

            #pragma unroll
            for (int T = 0; T < 2; ++T) {
                bf16x8 aw = *(const bf16x8*)(lds + OFF_W2 + (T * 4 + kt) * 512 + lane * 8);
                DV[T] = __builtin_amdgcn_mfma_f32_16x16x32_bf16(aw, bv, DV[T], 0, 0, 0);
            }
            #pragma unroll
            for (int t = 0; t < 4; ++t) {
                bf16x8 aH = *(const bf16x8*)(lds + OFF_W3H + (t * 4 + kt) * 512 + lane * 8);
                bf16x8 aL = *(const bf16x8*)(lds + OFF_W3L + (t * 4 + kt) * 512 + lane * 8);
                DC[t] = __builtin_amdgcn_mfma_f32_16x16x32_bf16(aH, bh, DC[t], 0, 0, 0);
                DC[t] = __builtin_amdgcn_mfma_f32_16x16x32_bf16(aH, bl, DC[t], 0, 0, 0);
                DC[t] = __builtin_amdgcn_mfma_f32_16x16x32_bf16(aL, bh, DC[t], 0, 0, 0);
            }
        }

        // ---- epilogue: per-lane 8 centroids of its own sample ---------------
        float2 av = ((const float2*)a)[wgbase + m0 + m];
        float num = 0.f, den = 0.f;
        #pragma unroll
        for (int t = 0; t < 4; ++t) {
            #pragma unroll
            for (int p = 0; p < 2; ++p) {
                float x = 5.f * tanh_fast(DC[t][2 * p]);
                float y = 5.f * tanh_fast(DC[t][2 * p + 1]);
                float ex = x - av.x, ey = y - av.y;
                float dist = sqrtf(fmaf(ex, ex, ey * ey));
                float wt = __expf(-3.f * dist);
                if (t == 3 && G == 3) wt = 0.f;      // n = 30,31 pad
                float v = (t < 2) ? DV[0][2 * t + p] : DV[1][2 * (t - 2) + p];
                num = fmaf(wt, v, num);
                den += wt;
            }
        }
        num += __shfl_xor(num, 16); den += __shfl_xor(den, 16);
        num += __shfl_xor(num, 32); den += __shfl_xor(den, 32);
        if (lane < 16) out[wgbase + m0 + m] = num / den;
    }
}

extern "C" void kernel_launch(void* const* d_in, const int* in_sizes, int n_in,
                              void* d_out, int out_size, void* d_ws, size_t ws_size,
                              hipStream_t stream) {
    const float* s   = (const float*)d_in[0];
    const float* a   = (const float*)d_in[1];
    const float* W1  = (const float*)d_in[2];
    const float* b1  = (const float*)d_in[3];
    const float* W2  = (const float*)d_in[4];
    const float* b2  = (const float*)d_in[5];
    const float* L1  = (const float*)d_in[6];
    const float* bl1 = (const float*)d_in[7];
    const float* WL2 = (const float*)d_in[8];
    const float* bL2 = (const float*)d_in[9];
    float* out = (float*)d_out;
    short* ws  = (short*)d_ws;

    prep_kernel<<<(TOT_SHORTS + 255) / 256, 256, 0, stream>>>(
        W1, b1, W2, b2, L1, bl1, WL2, bL2, ws);

    int Btot = out_size;                 // 524288
    int grid = Btot / 256;               // 2048 WGs, 64 samples/wave
    fused_kernel<<<grid, 256, 0, stream>>>(s, a, ws, out);
}

// Round 5
// 103.137 us; speedup vs baseline: 3.0538x; 1.5595x over previous
//
#include <hip/hip_runtime.h>

// ---------------------------------------------------------------------------
// Operand-swapped fully-fused MFMA kernel, zero h-LDS, spill-free.
//   GEMM1': D[c][m] = (W|b)^T s^T  -> h in transposed C layout, computed
//           INSIDE the kt loop (tiles 2kt, 2kt+1) so packed h words are
//           short-lived (no cross-loop live range -> no scratch spills).
//   exchange: pack h to bf16 pairs, 8 shfl + selects per stream per kt
//   GEMM2': D[n][m]; row mapping gives each lane complete (x,y,value)
//           triples for 8 centroids of its own sample.
// Weight fragments precomputed once into d_ws by prep_kernel; main kernel
// copies ws -> LDS (50.5 KB -> 3 WG/CU); no barriers in the mt loop.
// ---------------------------------------------------------------------------

typedef __attribute__((ext_vector_type(8))) short bf16x8;
typedef __attribute__((ext_vector_type(4))) float f32x4;

// short-index offsets inside ws / LDS
#define OFF_V1  0        // 7 half-tiles x 256 (value GEMM1' A, hi)
#define OFF_L1H 1792     // 7 half-tiles x 256 (loc GEMM1' A, hi)
#define OFF_L1L 3584     // 7 half-tiles x 256 (loc GEMM1' A, lo)
#define OFF_W2  5376     // 2 n-tiles x 4 kt x 512 (values GEMM2' A, hi)
#define OFF_W3H 9472     // 4 c-tiles x 4 kt x 512 (centroid GEMM2' A, hi)
#define OFF_W3L 17664    // same, lo
#define TOT_SHORTS 25856 // 51712 bytes

__device__ __forceinline__ short f2bf(float x) {
    union { float f; unsigned u; } v; v.f = x;
    unsigned r = v.u + 0x7FFFu + ((v.u >> 16) & 1u);   // RNE
    return (short)(r >> 16);
}
__device__ __forceinline__ float bf2f(short h) {
    union { unsigned u; float f; } v; v.u = ((unsigned)(unsigned short)h) << 16;
    return v.f;
}
__device__ __forceinline__ unsigned pack2(short lo, short hi) {
    return (unsigned)(unsigned short)lo | (((unsigned)(unsigned short)hi) << 16);
}
__device__ __forceinline__ float tanh_fast(float x) {
    float e = __expf(2.f * x);
    return 1.f - 2.f / (e + 1.f);
}

// ---------------- prologue: build fragment-layout weights in ws ------------
__global__ __launch_bounds__(256) void prep_kernel(
    const float* __restrict__ W1, const float* __restrict__ b1,
    const float* __restrict__ W2, const float* __restrict__ b2,
    const float* __restrict__ L1, const float* __restrict__ bl1,
    const float* __restrict__ WL2, const float* __restrict__ bL2,
    short* __restrict__ ws)
{
    int idx = blockIdx.x * 256 + threadIdx.x;
    if (idx >= TOT_SHORTS) return;
    float val = 0.f;
    bool want_lo = false;

    if (idx < OFF_W2) {
        // GEMM1' A half-tiles: [region r][tile t][lane 0..31][j 0..7]
        int r = idx / 1792;              // 0 = W1(hi), 1 = L1(hi), 2 = L1(lo)
        int rem = idx - r * 1792;
        int t = rem >> 8, e = rem & 255;
        int ln = e >> 3, j = e & 7;      // ln 0..31
        int c = t * 16 + (ln & 15);      // hidden unit (row of A)
        int k = (ln >> 4) * 8 + j;       // 0..15 (real k: 0..10)
        const float* W  = (r == 0) ? W1 : L1;
        const float* bb = (r == 0) ? b1 : bl1;
        if (c < 100)       val = (k < 10) ? W[k * 100 + c] : ((k == 10) ? bb[c] : 0.f);
        else if (c == 100) val = (k == 10) ? 1.f : 0.f;    // generates h[100]=1 bias row
        want_lo = (r == 2);
    } else if (idx < OFF_W3H) {
        // GEMM2a' A: [T 0..1][kt 0..3][lane 0..63][j]
        int i2 = idx - OFF_W2;
        int T = i2 >> 11, kt = (i2 >> 9) & 3, e = i2 & 511;
        int ln = e >> 3, j = e & 7;
        int rho = ln & 15;
        int k = kt * 32 + (ln >> 4) * 8 + j;
        int n = 16 * T + 2 * (rho >> 2) + ((rho & 3) >> 1) * 8 + (rho & 1);
        if (n < 30) val = (k < 100) ? W2[k * 30 + n] : ((k == 100) ? b2[n] : 0.f);
    } else {
        // GEMM2b' A: [half h][t 0..3][kt][lane][j]
        int i3 = idx - OFF_W3H;
        want_lo = (i3 >= 8192); i3 &= 8191;
        int t = i3 >> 11, kt = (i3 >> 9) & 3, e = i3 & 511;
        int ln = e >> 3, j = e & 7;
        int rho = ln & 15;
        int k = kt * 32 + (ln >> 4) * 8 + j;
        int n = 8 * t + 2 * (rho >> 2) + ((rho & 3) >> 1);
        int d = rho & 1;
        if (n < 30) val = (k < 100) ? WL2[(n * 100 + k) * 2 + d]
                                    : ((k == 100) ? bL2[n * 2 + d] : 0.f);
    }
    short hi = f2bf(val);
    ws[idx] = want_lo ? f2bf(val - bf2f(hi)) : hi;
}

// ---------------- main fused kernel ----------------------------------------
__global__ __launch_bounds__(256, 2) void fused_kernel(
    const float* __restrict__ s, const float* __restrict__ a,
    const short* __restrict__ ws, float* __restrict__ out)
{
    __shared__ short lds[TOT_SHORTS];
    const int tid  = threadIdx.x;
    const int lane = tid & 63;
    const int wave = tid >> 6;
    const int m    = lane & 15;
    const int G    = lane >> 4;
    const int wgbase = blockIdx.x * 256;

    // stage ws -> LDS (identity copy, 16B chunks)
    {
        const int4* g4 = (const int4*)ws;
        int4* l4 = (int4*)lds;
        for (int i = tid; i < TOT_SHORTS / 8; i += 256) l4[i] = g4[i];
    }
    __syncthreads();

    const int srcA = m | ((2 * (G & 1)) << 4);
    const int srcB = srcA | 16;
    const bool hiTile = (G >> 1) != 0;     // this lane's k-range lives in tile t0+1

    const bf16x8 bz = {0, 0, 0, 0, 0, 0, 0, 0};
    const f32x4 fz = {0.f, 0.f, 0.f, 0.f};

    for (int mt = 0; mt < 4; ++mt) {
        const int m0 = wave * 64 + mt * 16;

        // ---- B-frag of s^T (hi + lo); lanes>=32 zero; k=10 is bias-1 row ----
        bf16x8 sb_hi = bz, sb_lo = bz;
        {
            const float2* p = (const float2*)(s + (size_t)(wgbase + m0 + m) * 10);
            if (G == 0) {
                float2 q0 = p[0], q1 = p[1], q2 = p[2], q3 = p[3];
                float qs[8] = {q0.x, q0.y, q1.x, q1.y, q2.x, q2.y, q3.x, q3.y};
                #pragma unroll
                for (int i = 0; i < 8; ++i) {
                    short h = f2bf(qs[i]);
                    sb_hi[i] = h; sb_lo[i] = f2bf(qs[i] - bf2f(h));
                }
            } else if (G == 1) {
                float2 q4 = p[4];
                short hx = f2bf(q4.x), hy = f2bf(q4.y);
                sb_hi[0] = hx; sb_lo[0] = f2bf(q4.x - bf2f(hx));
                sb_hi[1] = hy; sb_lo[1] = f2bf(q4.y - bf2f(hy));
                sb_hi[2] = (short)0x3F80;  // k = 10 -> 1.0
            }
        }

        // GEMM1' one tile -> packed bf16 pair words (value, h-hi, h-lo)
        auto g1tile = [&](int t, unsigned& qv0, unsigned& qv1,
                          unsigned& qh0, unsigned& qh1,
                          unsigned& ql0, unsigned& ql1) {
            bf16x8 aV = bz, aH = bz, aL = bz;
            if (lane < 32) {
                aV = *(const bf16x8*)(lds + OFF_V1  + t * 256 + lane * 8);
                aH = *(const bf16x8*)(lds + OFF_L1H + t * 256 + lane * 8);
                aL = *(const bf16x8*)(lds + OFF_L1L + t * 256 + lane * 8);
            }
            f32x4 dv = __builtin_amdgcn_mfma_f32_16x16x32_bf16(aV, sb_hi, fz, 0, 0, 0);
            f32x4 dh = __builtin_amdgcn_mfma_f32_16x16x32_bf16(aH, sb_hi, fz, 0, 0, 0);
            dh = __builtin_amdgcn_mfma_f32_16x16x32_bf16(aH, sb_lo, dh, 0, 0, 0);
            dh = __builtin_amdgcn_mfma_f32_16x16x32_bf16(aL, sb_hi, dh, 0, 0, 0);

            float v0 = fmaxf(dv[0], 0.f), v1 = fmaxf(dv[1], 0.f);
            float v2 = fmaxf(dv[2], 0.f), v3 = fmaxf(dv[3], 0.f);
            qv0 = pack2(f2bf(v0), f2bf(v1));
            qv1 = pack2(f2bf(v2), f2bf(v3));

            float h0 = fmaxf(dh[0], 0.f), h1 = fmaxf(dh[1], 0.f);
            float h2 = fmaxf(dh[2], 0.f), h3 = fmaxf(dh[3], 0.f);
            short h0h = f2bf(h0), h1h = f2bf(h1), h2h = f2bf(h2), h3h = f2bf(h3);
            qh0 = pack2(h0h, h1h);
            qh1 = pack2(h2h, h3h);
            ql0 = pack2(f2bf(h0 - bf2f(h0h)), f2bf(h1 - bf2f(h1h)));
            ql1 = pack2(f2bf(h2 - bf2f(h2h)), f2bf(h3 - bf2f(h3h)));
        };

        // exchange: build GEMM2' B-frag for one kt from two tiles' pack words
        auto xch4 = [&](unsigned a0, unsigned a1, unsigned b0, unsigned b1,
                        bool hasT1) -> bf16x8 {
            unsigned e0 = (unsigned)__shfl((int)a0, srcA);
            unsigned e1 = (unsigned)__shfl((int)a1, srcA);
            unsigned e2 = (unsigned)__shfl((int)a0, srcB);
            unsigned e3 = (unsigned)__shfl((int)a1, srcB);
            unsigned f0 = 0, f1 = 0, f2 = 0, f3 = 0;
            if (hasT1) {
                f0 = (unsigned)__shfl((int)b0, srcA);
                f1 = (unsigned)__shfl((int)b1, srcA);
                f2 = (unsigned)__shfl((int)b0, srcB);
                f3 = (unsigned)__shfl((int)b1, srcB);
            }
            union { unsigned u[4]; bf16x8 v; } U;
            U.u[0] = hiTile ? f0 : e0;
            U.u[1] = hiTile ? f1 : e1;
            U.u[2] = hiTile ? f2 : e2;
            U.u[3] = hiTile ? f3 : e3;
            return U.v;
        };

        // ---- fused K loop: produce 2 GEMM1' tiles, exchange, consume --------
        f32x4 DV[2] = {fz, fz};
        f32x4 DC[4] = {fz, fz, fz, fz};
        #pragma unroll
        for (int kt = 0; kt < 4; ++kt) {
            const bool h1 = (kt < 3);
            unsigned Av0, Av1, Ah0, Ah1, Al0, Al1;
            unsigned Bv0 = 0, Bv1 = 0, Bh0 = 0, Bh1 = 0, Bl0 = 0, Bl1 = 0;
            g1tile(2 * kt, Av0, Av1, Ah0, Ah1, Al0, Al1);
            if (h1) g1tile(2 * kt + 1, Bv0, Bv1, Bh0, Bh1, Bl0, Bl1);

            bf16x8 bv = xch4(Av0, Av1, Bv0, Bv1, h1);
            bf16x8 bh = xch4(Ah0, Ah1, Bh0, Bh1, h1);
            bf16x8 bl = xch4(Al0, Al1, Bl0, Bl1, h1);

            #pragma unroll
            for (int T = 0; T < 2; ++T) {
                bf16x8 aw = *(const bf16x8*)(lds + OFF_W2 + (T * 4 + kt) * 512 + lane * 8);
                DV[T] = __builtin_amdgcn_mfma_f32_16x16x32_bf16(aw, bv, DV[T], 0, 0, 0);
            }
            #pragma unroll
            for (int t = 0; t < 4; ++t) {
                bf16x8 aH = *(const bf16x8*)(lds + OFF_W3H + (t * 4 + kt) * 512 + lane * 8);
                bf16x8 aL = *(const bf16x8*)(lds + OFF_W3L + (t * 4 + kt) * 512 + lane * 8);
                DC[t] = __builtin_amdgcn_mfma_f32_16x16x32_bf16(aH, bh, DC[t], 0, 0, 0);
                DC[t] = __builtin_amdgcn_mfma_f32_16x16x32_bf16(aH, bl, DC[t], 0, 0, 0);
                DC[t] = __builtin_amdgcn_mfma_f32_16x16x32_bf16(aL, bh, DC[t], 0, 0, 0);
            }
        }

        // ---- epilogue: per-lane 8 centroids of its own sample ---------------
        float2 av = ((const float2*)a)[wgbase + m0 + m];
        float num = 0.f, den = 0.f;
        #pragma unroll
        for (int t = 0; t < 4; ++t) {
            #pragma unroll
            for (int p = 0; p < 2; ++p) {
                float x = 5.f * tanh_fast(DC[t][2 * p]);
                float y = 5.f * tanh_fast(DC[t][2 * p + 1]);
                float ex = x - av.x, ey = y - av.y;
                float dist = sqrtf(fmaf(ex, ex, ey * ey));
                float wt = __expf(-3.f * dist);
                if (t == 3 && G == 3) wt = 0.f;      // n = 30,31 pad
                float v = (t < 2) ? DV[0][2 * t + p] : DV[1][2 * (t - 2) + p];
                num = fmaf(wt, v, num);
                den += wt;
            }
        }
        num += __shfl_xor(num, 16); den += __shfl_xor(den, 16);
        num += __shfl_xor(num, 32); den += __shfl_xor(den, 32);
        if (lane < 16) out[wgbase + m0 + m] = num / den;
    }
}

extern "C" void kernel_launch(void* const* d_in, const int* in_sizes, int n_in,
                              void* d_out, int out_size, void* d_ws, size_t ws_size,
                              hipStream_t stream) {
    const float* s   = (const float*)d_in[0];
    const float* a   = (const float*)d_in[1];
    const float* W1  = (const float*)d_in[2];
    const float* b1  = (const float*)d_in[3];
    const float* W2  = (const float*)d_in[4];
    const float* b2  = (const float*)d_in[5];
    const float* L1  = (const float*)d_in[6];
    const float* bl1 = (const float*)d_in[7];
    const float* WL2 = (const float*)d_in[8];
    const float* bL2 = (const float*)d_in[9];
    float* out = (float*)d_out;
    short* ws  = (short*)d_ws;

    prep_kernel<<<(TOT_SHORTS + 255) / 256, 256, 0, stream>>>(
        W1, b1, W2, b2, L1, bl1, WL2, bL2, ws);

    int Btot = out_size;                 // 524288
    int grid = Btot / 256;               // 2048 WGs, 64 samples/wave
    fused_kernel<<<grid, 256, 0, stream>>>(s, a, ws, out);
}